// Round 6
// baseline (598.286 us; speedup 1.0000x reference)
//
#include <hip/hip_runtime.h>
#include <hip/hip_bf16.h>
#include <math.h>

#define D_MODEL 256
#define D_STATE 16
#define D_INNER 512
#define DT_RANK 16
#define NB 4
#define NVAR 32
#define SEG 96
#define TOKENS (NB*NVAR*SEG)   /* 12288 */

typedef float f4 __attribute__((ext_vector_type(4)));

__device__ __forceinline__ float silu_f(float x) { return x / (1.0f + __expf(-x)); }

// ---------------------------------------------------------------------------
// Stage a BNx16 W-tile via global_load_lds (DMA, no VALU/ds_write cost).
// LDS layout [col][16k] in lane-linear order; the 16B k-chunk index is
// XOR-swizzled at the SOURCE: stored chunk c_st holds source chunk
// c_st ^ ((col>>1)&3).  Readers XOR the same key (both-sides swizzle).
// ---------------------------------------------------------------------------
template<int BN, int K>
__device__ __forceinline__ void stage_w(const float* __restrict__ Wg,
                                        float* wlds, int tid, int dbuf, int k0)
{
#pragma unroll
    for (int u = 0; u < BN / 64; u++) {
        int col  = u * 64 + (tid >> 2);
        int csrc = (tid & 3) ^ ((tid >> 3) & 3);   // source chunk for this slot
        int ldsw = __builtin_amdgcn_readfirstlane(dbuf * (BN * 16) + u * 1024 + (tid & ~63) * 4);
        __builtin_amdgcn_global_load_lds(
            (const __attribute__((address_space(1))) void*)(Wg + (size_t)col * K + k0 + 4 * csrc),
            (__attribute__((address_space(3))) void*)(wlds + ldsw), 16, 0, 0);
    }
}

// ---------------------------------------------------------------------------
// NT GEMM v3: C[m,n] = sum_k A[m,k] * W[n,k].
// 256 thr = 4 waves; BM=32 (wave owns 8 rows).  A fragments are wave-uniform
// -> s_load (scalar pipe, free).  W via DMA-staged LDS, read b128 ALONG k
// (4 k per read): per tile/wave only 4*CPL ds_read_b128 -> LDS pipe at ~75%,
// FMA-bound.  BK=16 double-buffered, one barrier per tile.
// Lane owns cols {g*64+lane}.  MODE 0 plain; 2: (b,v,s)->(b,s,v); 3: inverse.
// ---------------------------------------------------------------------------
template<int K, int BN, int MODE>
__global__ __launch_bounds__(256, 4)
void gemm_v3(const float* __restrict__ A, const float* __restrict__ W,
             float* __restrict__ C, int N)
{
    constexpr int NT  = K / 16;
    constexpr int CPL = BN / 64;
    __shared__ float wlds[2 * BN * 16];

    const int tid  = threadIdx.x;
    const int lane = tid & 63;
    const int wid  = __builtin_amdgcn_readfirstlane(tid >> 6);
    const int m0 = blockIdx.x * 32;
    const int n0 = blockIdx.y * BN;

    // wave-uniform A row pointers -> s_load fragments
    const float* Ar[8];
#pragma unroll
    for (int r = 0; r < 8; r++)
        Ar[r] = A + (size_t)(m0 + wid * 8 + r) * K;

    const float* Wg = W + (size_t)n0 * K;

    const int key = (lane >> 1) & 3;
    int wbase[CPL];
#pragma unroll
    for (int g = 0; g < CPL; g++) wbase[g] = (g * 64 + lane) * 16;

    float acc[8][CPL];
#pragma unroll
    for (int r = 0; r < 8; r++)
#pragma unroll
        for (int g = 0; g < CPL; g++) acc[r][g] = 0.0f;

    stage_w<BN, K>(Wg, wlds, tid, 0, 0);
    __syncthreads();                       // tile 0 resident

    for (int t = 0; t < NT; t++) {
        const int k0 = t * 16;
        if (t + 1 < NT)                    // issue next-tile DMA early
            stage_w<BN, K>(Wg, wlds, tid, (t + 1) & 1, k0 + 16);
        const float* Wb = wlds + (t & 1) * (BN * 16);
#pragma unroll
        for (int q = 0; q < 4; q++) {
            f4 a4[8];
#pragma unroll
            for (int r = 0; r < 8; r++)    // uniform -> s_load_dwordx4
                a4[r] = *(const f4*)(Ar[r] + k0 + 4 * q);
            f4 wv[CPL];
#pragma unroll
            for (int g = 0; g < CPL; g++)
                wv[g] = *(const f4*)(Wb + wbase[g] + 4 * (q ^ key));
#pragma unroll
            for (int r = 0; r < 8; r++)
#pragma unroll
                for (int g = 0; g < CPL; g++)
#pragma unroll
                    for (int e = 0; e < 4; e++)
                        acc[r][g] = fmaf(a4[r][e], wv[g][e], acc[r][g]);
        }
        __syncthreads();                   // drains DMA (vmcnt) + guards dbuf
    }

#pragma unroll
    for (int r = 0; r < 8; r++) {
        int m = m0 + wid * 8 + r;
        int orow = m;
        if (MODE == 2) {                   // (b*32+v)*96+s -> (b*96+s)*32+v
            int b = m / 3072, rr = m % 3072;
            int v = rr / 96, s = rr % 96;
            orow = (b * 96 + s) * 32 + v;
        } else if (MODE == 3) {            // (b*96+s)*32+v -> (b*32+v)*96+s
            int b = m / 3072, rr = m % 3072;
            int s = rr / 32, v = rr % 32;
            orow = (b * 32 + v) * 96 + s;
        }
        float* crow = C + (size_t)orow * N + n0;
#pragma unroll
        for (int g = 0; g < CPL; g++)
            crow[g * 64 + lane] = acc[r][g];
    }
}

// ---------------------------------------------------------------------------
// Small tiled NT GEMM (x_proj N=48, dt_proj K=16).
// MODE 0: plain.  MODE 1: softplus(acc + bias[n]).
// ---------------------------------------------------------------------------
template<int BM, int BN, int BK, int TM, int TN, int MODE>
__global__ __launch_bounds__(256)
void gemm_nt(const float* __restrict__ A, int lda,
             const float* __restrict__ W,
             float* __restrict__ C,
             const float* __restrict__ bias,
             int M, int N, int K)
{
    __shared__ float As[BK][BM + 4];
    __shared__ float Ws[BK][BN + 4];

    const int tid = threadIdx.x;
    const int tx  = tid % (BN / TN);
    const int ty  = tid / (BN / TN);
    const int m0  = blockIdx.x * BM;
    const int n0  = blockIdx.y * BN;

    float acc[TM][TN];
#pragma unroll
    for (int i = 0; i < TM; i++)
#pragma unroll
        for (int j = 0; j < TN; j++) acc[i][j] = 0.0f;

    constexpr int AF4 = (BM * BK) / 1024;
    constexpr int WF4 = (BN * BK) / 1024;
    constexpr int F4R = BK / 4;

    for (int k0 = 0; k0 < K; k0 += BK) {
#pragma unroll
        for (int c = 0; c < AF4; c++) {
            int idx = tid + c * 256;
            int row = idx / F4R;
            int kc  = (idx % F4R) * 4;
            float4 v = *(const float4*)(A + (size_t)(m0 + row) * lda + k0 + kc);
            As[kc + 0][row] = v.x;
            As[kc + 1][row] = v.y;
            As[kc + 2][row] = v.z;
            As[kc + 3][row] = v.w;
        }
#pragma unroll
        for (int c = 0; c < WF4; c++) {
            int idx = tid + c * 256;
            int row = idx / F4R;
            int kc  = (idx % F4R) * 4;
            float4 v;
            if (n0 + row < N) v = *(const float4*)(W + (size_t)(n0 + row) * K + k0 + kc);
            else              v = make_float4(0.f, 0.f, 0.f, 0.f);
            Ws[kc + 0][row] = v.x;
            Ws[kc + 1][row] = v.y;
            Ws[kc + 2][row] = v.z;
            Ws[kc + 3][row] = v.w;
        }
        __syncthreads();

#pragma unroll
        for (int kk = 0; kk < BK; kk++) {
            float a[TM], w[TN];
#pragma unroll
            for (int i = 0; i < TM; i++) a[i] = As[kk][ty * TM + i];
#pragma unroll
            for (int j = 0; j < TN; j++) w[j] = Ws[kk][tx * TN + j];
#pragma unroll
            for (int i = 0; i < TM; i++)
#pragma unroll
                for (int j = 0; j < TN; j++)
                    acc[i][j] = fmaf(a[i], w[j], acc[i][j]);
        }
        __syncthreads();
    }

#pragma unroll
    for (int i = 0; i < TM; i++) {
        int m = m0 + ty * TM + i;
#pragma unroll
        for (int j = 0; j < TN; j++) {
            int n = n0 + tx * TN + j;
            if (n < N) {
                float v = acc[i][j];
                if (MODE == 1) {
                    v += bias[n];
                    v = (v > 20.0f) ? v : log1pf(__expf(v));
                }
                C[(size_t)m * N + n] = v;
            }
        }
    }
}

// ---------------------------------------------------------------------------
// Depthwise causal conv (width 4) + bias + SiLU.
// ---------------------------------------------------------------------------
__global__ __launch_bounds__(256)
void conv_silu(const float* __restrict__ xz, const float* __restrict__ cw,
               const float* __restrict__ cb, float* __restrict__ xc, int L)
{
    int i = blockIdx.x * 256 + threadIdx.x;
    int e = i % D_INNER;
    int t = i / D_INNER;
    int l = t % L;
    float acc = cb[e];
#pragma unroll
    for (int j = 0; j < 4; j++) {
        int li = l - 3 + j;
        if (li >= 0) acc = fmaf(xz[(size_t)(t + li - l) * 1024 + e], cw[e * 4 + j], acc);
    }
    xc[i] = silu_f(acc);
}

// ---------------------------------------------------------------------------
// Selective scan + skip + gate, state-split 2x: lane pair (sh=0/8) each owns
// 8 states of channel e; partial y combined via shfl_xor(1).  2x occupancy,
// ~half the per-step dependent chain vs the 16-state version.
// ---------------------------------------------------------------------------
__global__ __launch_bounds__(256)
void scan_gate2(float* __restrict__ dty,
                const float* __restrict__ xc,
                const float* __restrict__ xz,
                const float* __restrict__ dbl,
                const float* __restrict__ A_log,
                const float* __restrict__ Dvec,
                int L)
{
    int bn = blockIdx.x >> 2;
    int e  = ((blockIdx.x & 3) << 7) + (threadIdx.x >> 1);
    int sh = (threadIdx.x & 1) << 3;       // state half: 0 or 8

    float Ae[8], h[8];
#pragma unroll
    for (int s = 0; s < 8; s++) {
        Ae[s] = -__expf(A_log[e * D_STATE + sh + s]);
        h[s]  = 0.0f;
    }
    const float De = Dvec[e];

    for (int l = 0; l < L; l++) {
        int tk = bn * L + l;
        float dtv = dty[(size_t)tk * 512 + e];
        float u   = xc [(size_t)tk * 512 + e];
        const float* bc = dbl + (size_t)tk * 48;
        float y = 0.0f;
#pragma unroll
        for (int s = 0; s < 8; s++) {
            float dA = __expf(dtv * Ae[s]);
            h[s] = fmaf(dA, h[s], dtv * bc[16 + sh + s] * u);
            y    = fmaf(h[s], bc[32 + sh + s], y);
        }
        y += __shfl_xor(y, 1);
        if (sh == 0) {
            float zv = xz[(size_t)tk * 1024 + 512 + e];
            dty[(size_t)tk * 512 + e] = (y + u * De) * silu_f(zv);
        }
    }
}

// ---------------------------------------------------------------------------
// One mamba stage.
// ---------------------------------------------------------------------------
template<int OUTMODE>
static void run_stage(const float* xin,
                      const float* in_w, const float* conv_w, const float* conv_b,
                      const float* xproj_w, const float* dt_w, const float* dt_b,
                      const float* A_log, const float* Dvec, const float* out_w,
                      float* xz, float* xc, float* dbl, float* dty, float* outp,
                      int Bn, int L, hipStream_t stream)
{
    const int M = TOKENS;
    // in_proj: [M,1024] = x[M,256] * in_w^T   (BN=256, grid 384x4)
    gemm_v3<256, 256, 0><<<dim3(M / 32, 1024 / 256), 256, 0, stream>>>(xin, in_w, xz, 1024);
    // conv + silu
    conv_silu<<<dim3((M * D_INNER) / 256), 256, 0, stream>>>(xz, conv_w, conv_b, xc, L);
    // x_proj: [M,48] = xc[M,512] * xproj_w^T  (384 blocks)
    gemm_nt<32,64,32,2,4,0><<<dim3(M / 32, 1), 256, 0, stream>>>(
        xc, 512, xproj_w, dbl, nullptr, M, 48, 512);
    // dt_proj + softplus
    gemm_nt<128,64,16,8,4,1><<<dim3(M / 128, 512 / 64), 256, 0, stream>>>(
        dbl, 48, dt_w, dty, dt_b, M, 512, 16);
    // scan + skip + gate (state-split 2x)
    scan_gate2<<<dim3(Bn * 4), 256, 0, stream>>>(dty, xc, xz, dbl, A_log, Dvec, L);
    // out_proj with fused layout transpose (BN=128, grid 384x2 = 768 blocks)
    gemm_v3<512, 128, OUTMODE><<<dim3(M / 32, 256 / 128), 256, 0, stream>>>(dty, out_w, outp, 256);
}

extern "C" void kernel_launch(void* const* d_in, const int* in_sizes, int n_in,
                              void* d_out, int out_size, void* d_ws, size_t ws_size,
                              hipStream_t stream)
{
    const float* x = (const float*)d_in[0];
    const float* t_in_w    = (const float*)d_in[1];
    const float* t_conv_w  = (const float*)d_in[2];
    const float* t_conv_b  = (const float*)d_in[3];
    const float* t_xproj_w = (const float*)d_in[4];
    const float* t_dt_w    = (const float*)d_in[5];
    const float* t_dt_b    = (const float*)d_in[6];
    const float* t_A_log   = (const float*)d_in[7];
    const float* t_D       = (const float*)d_in[8];
    const float* t_out_w   = (const float*)d_in[9];
    const float* d_in_w    = (const float*)d_in[10];
    const float* d_conv_w  = (const float*)d_in[11];
    const float* d_conv_b  = (const float*)d_in[12];
    const float* d_xproj_w = (const float*)d_in[13];
    const float* d_dt_w    = (const float*)d_in[14];
    const float* d_dt_b    = (const float*)d_in[15];
    const float* d_A_log   = (const float*)d_in[16];
    const float* d_D       = (const float*)d_in[17];
    const float* d_out_w   = (const float*)d_in[18];

    float* ws  = (float*)d_ws;
    float* xz  = ws;
    float* xc  = xz  + (size_t)TOKENS * 1024;
    float* dbl = xc  + (size_t)TOKENS * 512;
    float* dty = dbl + (size_t)TOKENS * 48;
    float* xt  = dty + (size_t)TOKENS * 512;
    const size_t need_bytes = ((size_t)TOKENS * (1024 + 512 + 48 + 512 + 256)) * 4;
    if (ws_size < need_bytes) return;

    // stage 1: time scan, Bn = 128, L = 96
    run_stage<2>(x, t_in_w, t_conv_w, t_conv_b, t_xproj_w, t_dt_w, t_dt_b,
                 t_A_log, t_D, t_out_w, xz, xc, dbl, dty, xt,
                 NB * NVAR, SEG, stream);
    // stage 2: dimension scan, Bn = 384, L = 32
    run_stage<3>(xt, d_in_w, d_conv_w, d_conv_b, d_xproj_w, d_dt_w, d_dt_b,
                 d_A_log, d_D, d_out_w, xz, xc, dbl, dty, (float*)d_out,
                 NB * SEG, NVAR, stream);
}

// Round 7
// 544.525 us; speedup vs baseline: 1.0987x; 1.0987x over previous
//
#include <hip/hip_runtime.h>
#include <hip/hip_bf16.h>
#include <math.h>

#define D_MODEL 256
#define D_STATE 16
#define D_INNER 512
#define DT_RANK 16
#define NB 4
#define NVAR 32
#define SEG 96
#define TOKENS (NB*NVAR*SEG)   /* 12288 */

typedef float f4 __attribute__((ext_vector_type(4)));

__device__ __forceinline__ float silu_f(float x) { return x / (1.0f + __expf(-x)); }

// ---------------------------------------------------------------------------
// WT[k][n] = W[n][k].  W: [N][K].  grid (K/32, N/32), block 256.
// ---------------------------------------------------------------------------
__global__ __launch_bounds__(256)
void transpose_w(const float* __restrict__ W, float* __restrict__ WT, int N, int K)
{
    __shared__ float t[32][33];
    const int k0 = blockIdx.x * 32, n0 = blockIdx.y * 32;
    const int tx = threadIdx.x & 31, ty = threadIdx.x >> 5;
#pragma unroll
    for (int i = 0; i < 32; i += 8)
        t[ty + i][tx] = W[(size_t)(n0 + ty + i) * K + k0 + tx];
    __syncthreads();
#pragma unroll
    for (int i = 0; i < 32; i += 8)
        WT[(size_t)(k0 + ty + i) * N + n0 + tx] = t[tx][ty + i];
}

// ---------------------------------------------------------------------------
// NT GEMM v4: C[m,n] = sum_k A[m,k] * WT[k][n]  (WT is pre-transposed W).
// 256 thr = 4 waves; BM=32 (wave owns 8 rows; A fragments wave-uniform ->
// scalar s_load pipe).  W: coalesced global_load_lds DMA of k-major rows
// into linear LDS [16][BN] (no ds_write, no swizzle), double-buffered.
// Inner: per k one conflict-free ds_read (CPL floats at CPL*lane) feeding
// 8*CPL FMA.  Per wave/tile: 1024 FMA-cyc vs 128 LDS-cyc -> FMA-bound.
// MODE 0 plain; 2: rows (b,v,s)->(b,s,v); 3: inverse.
// ---------------------------------------------------------------------------
template<int K, int BN, int MODE>
__global__ __launch_bounds__(256, 4)
void gemm_v4(const float* __restrict__ A, const float* __restrict__ WT,
             float* __restrict__ C, int N)
{
    constexpr int NT  = K / 16;
    constexpr int CPL = BN / 64;                 // 4 (BN=256) or 2 (BN=128)
    constexpr int KRD = 1024 / (BN * 4);         // k-rows per 1KB DMA: 1 or 2
    typedef float cvec __attribute__((ext_vector_type(CPL)));
    __shared__ float wlds[2 * 16 * BN];

    const int tid  = threadIdx.x;
    const int lane = tid & 63;
    const int wid  = __builtin_amdgcn_readfirstlane(tid >> 6);
    const int m0 = blockIdx.x * 32;
    const int n0 = blockIdx.y * BN;

    // wave-uniform A row pointers -> s_load fragments (scalar pipe)
    const float* Ar[8];
#pragma unroll
    for (int r = 0; r < 8; r++)
        Ar[r] = A + (size_t)(m0 + wid * 8 + r) * K;

    // coalesced DMA: each instr stages KRD k-rows (1 KB) of WT
    auto stage = [&](int dbuf, int k0) {
#pragma unroll
        for (int j = 0; j < 4 / KRD; j++) {
            int kb   = (wid * (4 / KRD) + j) * KRD;
            int krow = (KRD == 2) ? kb + (lane >> 5) : kb;
            int nofs = ((KRD == 2) ? (lane & 31) : lane) * 4;
            int dstw = __builtin_amdgcn_readfirstlane(dbuf * (16 * BN) + kb * BN);
            __builtin_amdgcn_global_load_lds(
                (const __attribute__((address_space(1))) void*)
                    (WT + (size_t)(k0 + krow) * N + n0 + nofs),
                (__attribute__((address_space(3))) void*)(wlds + dstw), 16, 0, 0);
        }
    };

    float acc[8][CPL];
#pragma unroll
    for (int r = 0; r < 8; r++)
#pragma unroll
        for (int g = 0; g < CPL; g++) acc[r][g] = 0.0f;

    stage(0, 0);
    __syncthreads();                             // tile 0 resident

    for (int t = 0; t < NT; t++) {
        const int k0 = t * 16;
        if (t + 1 < NT) stage((t + 1) & 1, k0 + 16);   // issue-early
        const float* Wb = wlds + (t & 1) * (16 * BN);
#pragma unroll
        for (int q = 0; q < 4; q++) {
            f4 a4[8];
#pragma unroll
            for (int r = 0; r < 8; r++)          // uniform -> s_load_dwordx4
                a4[r] = *(const f4*)(Ar[r] + k0 + 4 * q);
#pragma unroll
            for (int e = 0; e < 4; e++) {
                cvec wv = *(const cvec*)(Wb + (4 * q + e) * BN + CPL * lane);
#pragma unroll
                for (int r = 0; r < 8; r++)
#pragma unroll
                    for (int g = 0; g < CPL; g++)
                        acc[r][g] = fmaf(a4[r][e], wv[g], acc[r][g]);
            }
        }
        __syncthreads();                         // drains DMA + guards dbuf
    }

#pragma unroll
    for (int r = 0; r < 8; r++) {
        int m = m0 + wid * 8 + r;
        int orow = m;
        if (MODE == 2) {                         // (b*32+v)*96+s -> (b*96+s)*32+v
            int b = m / 3072, rr = m % 3072;
            int v = rr / 96, s = rr % 96;
            orow = (b * 96 + s) * 32 + v;
        } else if (MODE == 3) {                  // (b*96+s)*32+v -> (b*32+v)*96+s
            int b = m / 3072, rr = m % 3072;
            int s = rr / 32, v = rr % 32;
            orow = (b * 32 + v) * 96 + s;
        }
        cvec v;
#pragma unroll
        for (int g = 0; g < CPL; g++) v[g] = acc[r][g];
        *(cvec*)(C + (size_t)orow * N + n0 + CPL * lane) = v;
    }
}

// ---------------------------------------------------------------------------
// Small tiled NT GEMM (x_proj N=48, dt_proj K=16).
// MODE 0: plain.  MODE 1: softplus(acc + bias[n]).
// ---------------------------------------------------------------------------
template<int BM, int BN, int BK, int TM, int TN, int MODE>
__global__ __launch_bounds__(256)
void gemm_nt(const float* __restrict__ A, int lda,
             const float* __restrict__ W,
             float* __restrict__ C,
             const float* __restrict__ bias,
             int M, int N, int K)
{
    __shared__ float As[BK][BM + 4];
    __shared__ float Ws[BK][BN + 4];

    const int tid = threadIdx.x;
    const int tx  = tid % (BN / TN);
    const int ty  = tid / (BN / TN);
    const int m0  = blockIdx.x * BM;
    const int n0  = blockIdx.y * BN;

    float acc[TM][TN];
#pragma unroll
    for (int i = 0; i < TM; i++)
#pragma unroll
        for (int j = 0; j < TN; j++) acc[i][j] = 0.0f;

    constexpr int AF4 = (BM * BK) / 1024;
    constexpr int WF4 = (BN * BK) / 1024;
    constexpr int F4R = BK / 4;

    for (int k0 = 0; k0 < K; k0 += BK) {
#pragma unroll
        for (int c = 0; c < AF4; c++) {
            int idx = tid + c * 256;
            int row = idx / F4R;
            int kc  = (idx % F4R) * 4;
            float4 v = *(const float4*)(A + (size_t)(m0 + row) * lda + k0 + kc);
            As[kc + 0][row] = v.x;
            As[kc + 1][row] = v.y;
            As[kc + 2][row] = v.z;
            As[kc + 3][row] = v.w;
        }
#pragma unroll
        for (int c = 0; c < WF4; c++) {
            int idx = tid + c * 256;
            int row = idx / F4R;
            int kc  = (idx % F4R) * 4;
            float4 v;
            if (n0 + row < N) v = *(const float4*)(W + (size_t)(n0 + row) * K + k0 + kc);
            else              v = make_float4(0.f, 0.f, 0.f, 0.f);
            Ws[kc + 0][row] = v.x;
            Ws[kc + 1][row] = v.y;
            Ws[kc + 2][row] = v.z;
            Ws[kc + 3][row] = v.w;
        }
        __syncthreads();

#pragma unroll
        for (int kk = 0; kk < BK; kk++) {
            float a[TM], w[TN];
#pragma unroll
            for (int i = 0; i < TM; i++) a[i] = As[kk][ty * TM + i];
#pragma unroll
            for (int j = 0; j < TN; j++) w[j] = Ws[kk][tx * TN + j];
#pragma unroll
            for (int i = 0; i < TM; i++)
#pragma unroll
                for (int j = 0; j < TN; j++)
                    acc[i][j] = fmaf(a[i], w[j], acc[i][j]);
        }
        __syncthreads();
    }

#pragma unroll
    for (int i = 0; i < TM; i++) {
        int m = m0 + ty * TM + i;
#pragma unroll
        for (int j = 0; j < TN; j++) {
            int n = n0 + tx * TN + j;
            if (n < N) {
                float v = acc[i][j];
                if (MODE == 1) {
                    v += bias[n];
                    v = (v > 20.0f) ? v : log1pf(__expf(v));
                }
                C[(size_t)m * N + n] = v;
            }
        }
    }
}

// ---------------------------------------------------------------------------
// Depthwise causal conv (width 4) + bias + SiLU.
// ---------------------------------------------------------------------------
__global__ __launch_bounds__(256)
void conv_silu(const float* __restrict__ xz, const float* __restrict__ cw,
               const float* __restrict__ cb, float* __restrict__ xc, int L)
{
    int i = blockIdx.x * 256 + threadIdx.x;
    int e = i % D_INNER;
    int t = i / D_INNER;
    int l = t % L;
    float acc = cb[e];
#pragma unroll
    for (int j = 0; j < 4; j++) {
        int li = l - 3 + j;
        if (li >= 0) acc = fmaf(xz[(size_t)(t + li - l) * 1024 + e], cw[e * 4 + j], acc);
    }
    xc[i] = silu_f(acc);
}

// ---------------------------------------------------------------------------
// Selective scan + skip + gate, state-split 2x: lane pair (sh=0/8) each owns
// 8 states of channel e; partial y combined via shfl_xor(1).
// ---------------------------------------------------------------------------
__global__ __launch_bounds__(256)
void scan_gate2(float* __restrict__ dty,
                const float* __restrict__ xc,
                const float* __restrict__ xz,
                const float* __restrict__ dbl,
                const float* __restrict__ A_log,
                const float* __restrict__ Dvec,
                int L)
{
    int bn = blockIdx.x >> 2;
    int e  = ((blockIdx.x & 3) << 7) + (threadIdx.x >> 1);
    int sh = (threadIdx.x & 1) << 3;       // state half: 0 or 8

    float Ae[8], h[8];
#pragma unroll
    for (int s = 0; s < 8; s++) {
        Ae[s] = -__expf(A_log[e * D_STATE + sh + s]);
        h[s]  = 0.0f;
    }
    const float De = Dvec[e];

    for (int l = 0; l < L; l++) {
        int tk = bn * L + l;
        float dtv = dty[(size_t)tk * 512 + e];
        float u   = xc [(size_t)tk * 512 + e];
        const float* bc = dbl + (size_t)tk * 48;
        float y = 0.0f;
#pragma unroll
        for (int s = 0; s < 8; s++) {
            float dA = __expf(dtv * Ae[s]);
            h[s] = fmaf(dA, h[s], dtv * bc[16 + sh + s] * u);
            y    = fmaf(h[s], bc[32 + sh + s], y);
        }
        y += __shfl_xor(y, 1);
        if (sh == 0) {
            float zv = xz[(size_t)tk * 1024 + 512 + e];
            dty[(size_t)tk * 512 + e] = (y + u * De) * silu_f(zv);
        }
    }
}

// ---------------------------------------------------------------------------
// One mamba stage (weights pre-transposed to k-major).
// ---------------------------------------------------------------------------
template<int OUTMODE>
static void run_stage(const float* xin,
                      const float* in_wT, const float* conv_w, const float* conv_b,
                      const float* xproj_w, const float* dt_w, const float* dt_b,
                      const float* A_log, const float* Dvec, const float* out_wT,
                      float* xz, float* xc, float* dbl, float* dty, float* outp,
                      int Bn, int L, hipStream_t stream)
{
    const int M = TOKENS;
    // in_proj: [M,1024] = x[M,256] * in_w^T   (BN=256, grid 384x4)
    gemm_v4<256, 256, 0><<<dim3(M / 32, 1024 / 256), 256, 0, stream>>>(xin, in_wT, xz, 1024);
    // conv + silu
    conv_silu<<<dim3((M * D_INNER) / 256), 256, 0, stream>>>(xz, conv_w, conv_b, xc, L);
    // x_proj: [M,48] = xc[M,512] * xproj_w^T  (384 blocks)
    gemm_nt<32,64,32,2,4,0><<<dim3(M / 32, 1), 256, 0, stream>>>(
        xc, 512, xproj_w, dbl, nullptr, M, 48, 512);
    // dt_proj + softplus
    gemm_nt<128,64,16,8,4,1><<<dim3(M / 128, 512 / 64), 256, 0, stream>>>(
        dbl, 48, dt_w, dty, dt_b, M, 512, 16);
    // scan + skip + gate (state-split 2x)
    scan_gate2<<<dim3(Bn * 4), 256, 0, stream>>>(dty, xc, xz, dbl, A_log, Dvec, L);
    // out_proj with fused layout transpose (BN=128, grid 384x2)
    gemm_v4<512, 128, OUTMODE><<<dim3(M / 32, 256 / 128), 256, 0, stream>>>(dty, out_wT, outp, 256);
}

extern "C" void kernel_launch(void* const* d_in, const int* in_sizes, int n_in,
                              void* d_out, int out_size, void* d_ws, size_t ws_size,
                              hipStream_t stream)
{
    const float* x = (const float*)d_in[0];
    const float* t_in_w    = (const float*)d_in[1];
    const float* t_conv_w  = (const float*)d_in[2];
    const float* t_conv_b  = (const float*)d_in[3];
    const float* t_xproj_w = (const float*)d_in[4];
    const float* t_dt_w    = (const float*)d_in[5];
    const float* t_dt_b    = (const float*)d_in[6];
    const float* t_A_log   = (const float*)d_in[7];
    const float* t_D       = (const float*)d_in[8];
    const float* t_out_w   = (const float*)d_in[9];
    const float* d_in_w    = (const float*)d_in[10];
    const float* d_conv_w  = (const float*)d_in[11];
    const float* d_conv_b  = (const float*)d_in[12];
    const float* d_xproj_w = (const float*)d_in[13];
    const float* d_dt_w    = (const float*)d_in[14];
    const float* d_dt_b    = (const float*)d_in[15];
    const float* d_A_log   = (const float*)d_in[16];
    const float* d_D       = (const float*)d_in[17];
    const float* d_out_w   = (const float*)d_in[18];

    float* ws  = (float*)d_ws;
    float* xz  = ws;
    float* xc  = xz  + (size_t)TOKENS * 1024;
    float* dbl = xc  + (size_t)TOKENS * 512;
    float* dty = dbl + (size_t)TOKENS * 48;
    float* xt  = dty + (size_t)TOKENS * 512;
    float* t_in_wT  = xt + (size_t)TOKENS * 256;     // [256][1024]
    float* t_out_wT = t_in_wT  + 262144;             // [512][256]
    float* d_in_wT  = t_out_wT + 131072;             // [256][1024]
    float* d_out_wT = d_in_wT  + 262144;             // [512][256]
    const size_t need_bytes =
        ((size_t)TOKENS * (1024 + 512 + 48 + 512 + 256) + 2 * (262144 + 131072)) * 4;
    if (ws_size < need_bytes) return;

    // pre-transpose the four big weights to k-major
    transpose_w<<<dim3(256 / 32, 1024 / 32), 256, 0, stream>>>(t_in_w,  t_in_wT,  1024, 256);
    transpose_w<<<dim3(512 / 32,  256 / 32), 256, 0, stream>>>(t_out_w, t_out_wT,  256, 512);
    transpose_w<<<dim3(256 / 32, 1024 / 32), 256, 0, stream>>>(d_in_w,  d_in_wT,  1024, 256);
    transpose_w<<<dim3(512 / 32,  256 / 32), 256, 0, stream>>>(d_out_w, d_out_wT,  256, 512);

    // stage 1: time scan, Bn = 128, L = 96
    run_stage<2>(x, t_in_wT, t_conv_w, t_conv_b, t_xproj_w, t_dt_w, t_dt_b,
                 t_A_log, t_D, t_out_wT, xz, xc, dbl, dty, xt,
                 NB * NVAR, SEG, stream);
    // stage 2: dimension scan, Bn = 384, L = 32
    run_stage<3>(xt, d_in_wT, d_conv_w, d_conv_b, d_xproj_w, d_dt_w, d_dt_b,
                 d_A_log, d_D, d_out_wT, xz, xc, dbl, dty, (float*)d_out,
                 NB * SEG, NVAR, stream);
}